// Round 4
// baseline (41.099 us; speedup 1.0000x reference)
//
#include <hip/hip_runtime.h>
#include <math.h>

#define BB 2
#define LL 1024
#define DD 256
#define UU 32
#define RPB 4                  // rows per block
#define UNION (128 + RPB - 1)  // 131-row union band
#define KPAD 33                // bank(jru*33+u) = (jru+u)%32 -> max 2-way alias = free
#define APAD 132
#define TPB 1024
// prescale so tanh(v) = 1 - 2*rcp(exp2(SC*v)+1), SC = 2*log2(e)
#define SCALE 2.88539008177793f

// q[row,u] = SC * (x[row,:].Wt[:,u]);  k[row,u] = SC * (x[row,:].Wx[:,u] + bh[u])
// 2 rows/block, d split across lane pairs -> 1024 blocks, 16 waves/CU.
__global__ __launch_bounds__(256) void qk_kernel(
    const float* __restrict__ x, const float* __restrict__ Wt,
    const float* __restrict__ Wx, const float* __restrict__ bh,
    float* __restrict__ q, float* __restrict__ k)
{
    int t = threadIdx.x;
    int r1 = t >> 7;            // 2 rows per block
    int cu = (t >> 1) & 63;     // 0-31: q column, 32-63: k column (wave-uniform)
    int half = t & 1;           // d-range half (lane pair)
    int row = blockIdx.x * 2 + r1;
    bool isq = (cu < 32);
    int u = cu & 31;
    const float* W = (isq ? Wt : Wx) + (size_t)(half * 128) * UU + u;
    const float* xr = x + (size_t)row * DD + half * 128;
    float acc = 0.0f;
    #pragma unroll 8
    for (int d = 0; d < 128; ++d)
        acc = fmaf(xr[d], W[(size_t)d * UU], acc);
    acc += __shfl_xor(acc, 1);  // combine the two d-halves
    if (half == 0) {
        if (isq) q[(size_t)row * UU + u] = SCALE * acc;
        else     k[(size_t)row * UU + u] = SCALE * (acc + bh[u]);
    }
}

// One block per 4 consecutive output rows. 1024 threads, 2 blocks/CU (32 waves).
__global__ __launch_bounds__(TPB, 8) void attn_kernel(
    const float* __restrict__ x, const float* __restrict__ q,
    const float* __restrict__ k, const float* __restrict__ Wa,
    const float* __restrict__ ba, float* __restrict__ out)
{
    __shared__ float s_k[UNION * KPAD];   // prescaled k band, union-indexed
    __shared__ float s_a[RPB * APAD];     // unnormalized e, zero-padded
    __shared__ float s_q[RPB * UU];       // prescaled q
    __shared__ float s_wa[UU];
    __shared__ float s_c0;                // ba + sum(Wa)

    int t = threadIdx.x;
    int blk = blockIdx.x;                 // 0 .. B*L/RPB - 1
    int i0 = (blk * RPB) & (LL - 1);
    int b  = (blk * RPB) >> 10;           // / LL
    int rowbase = b * LL + i0;
    int j0 = i0 - 64;                     // union band start (signed)

    // ---- staging ----
    if (t < RPB * UU) s_q[t] = q[(size_t)rowbase * UU + t];
    if (t >= 64 && t < 64 + UU) s_wa[t - 64] = Wa[t - 64];
    if (t == 0) {
        float sw = ba[0];
        #pragma unroll
        for (int u = 0; u < UU; ++u) sw += Wa[u];
        s_c0 = sw;
    }
    if (t < RPB * APAD) s_a[t] = 0.0f;
    for (int idx = t; idx < UNION * UU; idx += TPB) {
        int jru = idx >> 5, u = idx & 31;
        int j = j0 + jru;
        if (0 <= j && j < LL)
            s_k[jru * KPAD + u] = k[(size_t)(b * LL + j) * UU + u];
    }
    __syncthreads();

    // ---- Phase 1: 512 e-entries, 2 threads each (16 u per thread) ----
    {
        int entry = t >> 1, half = t & 1;
        int r = entry >> 7, jr = entry & 127;
        int j = j0 + r + jr;              // band condition == j in [0,LL)
        int jru = r + jr;
        float acc = 0.0f;
        if (0 <= j && j < LL) {
            const float* kp = &s_k[jru * KPAD + half * 16];
            const float* qp = &s_q[r * UU + half * 16];
            const float* wp = &s_wa[half * 16];
            #pragma unroll
            for (int u = 0; u < 16; ++u) {
                float rcp = __builtin_amdgcn_rcpf(
                    __builtin_amdgcn_exp2f(qp[u] + kp[u]) + 1.0f);
                acc = fmaf(wp[u], rcp, acc);
            }
        }
        acc += __shfl_xor(acc, 1);        // pair shares same j
        if (half == 0 && 0 <= j && j < LL)
            s_a[r * APAD + jru] = __expf(fmaf(-2.0f, acc, s_c0));
    }
    __syncthreads();

    // ---- Phase 3: thread owns (d, r); denominator folded into the loop ----
    {
        int d = t >> 2, r = t & 3;        // 4-lane quads share d's x address
        const float* xb = x + (size_t)(b * LL) * DD + d;
        const float* ap = &s_a[r * APAD];
        float acc = 0.0f, ssum = 0.0f;
        int lo = max(0, -j0);
        int hi = min(UNION, LL - j0);     // block-uniform bounds, no inner branch
        #pragma unroll 4
        for (int jru = lo; jru < hi; ++jru) {
            float a = ap[jru];
            acc = fmaf(a, xb[(size_t)(j0 + jru) * DD], acc);
            ssum += a;                    // zero-padded entries contribute 0
        }
        out[(size_t)(rowbase + r) * DD + d] =
            acc * __builtin_amdgcn_rcpf(ssum + 1e-7f);
    }
}

extern "C" void kernel_launch(void* const* d_in, const int* in_sizes, int n_in,
                              void* d_out, int out_size, void* d_ws, size_t ws_size,
                              hipStream_t stream) {
    const float* x  = (const float*)d_in[0];
    const float* Wt = (const float*)d_in[1];
    const float* Wx = (const float*)d_in[2];
    const float* bh = (const float*)d_in[3];
    const float* Wa = (const float*)d_in[4];
    const float* ba = (const float*)d_in[5];
    float* out = (float*)d_out;

    float* q  = (float*)d_ws;                      // B*L*U floats (prescaled)
    float* kk = q + (size_t)BB * LL * UU;          // B*L*U floats (prescaled)

    qk_kernel<<<(BB * LL) / 2, 256, 0, stream>>>(x, Wt, Wx, bh, q, kk);
    attn_kernel<<<(BB * LL) / RPB, TPB, 0, stream>>>(x, q, kk, Wa, ba, out);
}